// Round 16
// baseline (386.993 us; speedup 1.0000x reference)
//
#include <hip/hip_runtime.h>
#include <math.h>

typedef unsigned short u16;
typedef __attribute__((ext_vector_type(8))) short s16x8;
typedef __attribute__((ext_vector_type(4))) float f32x4;
typedef __attribute__((ext_vector_type(16))) float f32x16;
typedef unsigned u32x2u __attribute__((ext_vector_type(2)));

// ---------- constants ----------
#define B_  2
#define S_  2048
#define H_  2048
#define D_  128
#define NQ_ 16
#define NKV_ 4
#define M_  (B_*S_)        // 4096
#define NQKV_ 3072         // NQ*D + 2*NKV*D

#define MFMA16(a,b,c) __builtin_amdgcn_mfma_f32_16x16x32_bf16(a,b,c,0,0,0)
#define MFMA32(a,b,c) __builtin_amdgcn_mfma_f32_32x32x16_bf16(a,b,c,0,0,0)

__device__ __forceinline__ u16 f2bf(float x) {
  union { float f; unsigned u; } v; v.f = x;
  unsigned r = v.u + 0x7fffu + ((v.u >> 16) & 1u);
  return (u16)(r >> 16);
}
__device__ __forceinline__ float bf2f(u16 x) {
  union { unsigned u; float f; } v; v.u = ((unsigned)x) << 16;
  return v.f;
}

__device__ __forceinline__ unsigned cvtpk(float lo, float hi) {
  unsigned r;
  asm("v_cvt_pk_bf16_f32 %0, %1, %2" : "=v"(r) : "v"(lo), "v"(hi));
  return r;
}

// T12: exchange half-waves: x' = {x.row0, y.row0}, y' = {x.row1, y.row1}
__device__ __forceinline__ void plswap(unsigned &x, unsigned &y) {
#if __has_builtin(__builtin_amdgcn_permlane32_swap)
  u32x2u r = __builtin_amdgcn_permlane32_swap(x, y, false, false);
  x = r[0]; y = r[1];
#else
  const bool hb = (threadIdx.x & 32) != 0;
  unsigned ex = (unsigned)__shfl_xor((int)x, 32, 64);
  unsigned ey = (unsigned)__shfl_xor((int)y, 32, 64);
  unsigned nx = hb ? ey : x;
  unsigned ny = hb ? y : ex;
  x = nx; y = ny;
#endif
}

__device__ __forceinline__ void gload_lds16(const u16* src, u16* dst) {
  __builtin_amdgcn_global_load_lds(
      (const __attribute__((address_space(1))) unsigned int*)src,
      (__attribute__((address_space(3))) unsigned int*)dst, 16, 0, 0);
}

// ---------- elementwise fp32 -> bf16 ----------
__global__ __launch_bounds__(256) void cvt_x(const float* __restrict__ X, u16* __restrict__ Xb, long n4) {
  const f32x4* X4 = (const f32x4*)X;
  for (long i = (long)blockIdx.x*256 + threadIdx.x; i < n4; i += (long)gridDim.x*256) {
    f32x4 v = X4[i];
    union { u16 u[4]; unsigned long long ll; } p;
    p.u[0] = f2bf(v[0]); p.u[1] = f2bf(v[1]); p.u[2] = f2bf(v[2]); p.u[3] = f2bf(v[3]);
    ((unsigned long long*)Xb)[i] = p.ll;
  }
}

// ---------- transpose + convert: W [K][N] fp32 -> Wt [N][K] bf16 ----------
__global__ __launch_bounds__(256) void wtrans(const float* __restrict__ W, u16* __restrict__ Wt,
                                              int N, int K) {
  __shared__ float t[32][33];
  const int n0 = blockIdx.x*32, k0 = blockIdx.y*32;
  const int tx = threadIdx.x, ty = threadIdx.y;   // (32,8)
  #pragma unroll
  for (int i = 0; i < 32; i += 8) t[ty+i][tx] = W[(long)(k0+ty+i)*N + n0 + tx];
  __syncthreads();
  #pragma unroll
  for (int i = 0; i < 32; i += 8) Wt[(long)(n0+ty+i)*K + k0 + tx] = f2bf(t[tx][ty+i]);
}

// ---------- V transpose: QKV bf16 v-part -> Vt bf16 [B][NKV][D][S] ----------
__global__ __launch_bounds__(256) void vtrans(const u16* __restrict__ QKV, u16* __restrict__ Vt) {
  __shared__ u16 t[32][33];
  const int bk = blockIdx.z;            // b*4+kvh
  const int s0 = blockIdx.x*32, d0 = blockIdx.y*32;
  const int tx = threadIdx.x, ty = threadIdx.y;
  const int b = bk >> 2, kvh = bk & 3;
  #pragma unroll
  for (int i = 0; i < 32; i += 8)
    t[ty+i][tx] = QKV[(long)(b*S_ + s0+ty+i)*NQKV_ + 2560 + kvh*128 + d0 + tx];
  __syncthreads();
  #pragma unroll
  for (int i = 0; i < 32; i += 8)
    Vt[((long)bk*D_ + d0+ty+i)*S_ + s0 + tx] = t[tx][ty+i];
}

// ---------- bias concat ----------
__global__ void concat_bias(const float* bq, const float* bk, const float* bv, float* bqkv) {
  int i = blockIdx.x*256 + threadIdx.x;
  if (i < NQKV_)
    bqkv[i] = (i < 2048) ? bq[i] : ((i < 2560) ? bk[i-2048] : bv[i-2560]);
}

// ---------- rope tables (exp2 instead of powf) ----------
__global__ void rope_tab(float* __restrict__ cosb, float* __restrict__ sinb) {
  int i = blockIdx.x*256 + threadIdx.x;   // 2048*64
  int t = i >> 6, d = i & 63;
  // 10000^(-d/64) = exp2(-d * log2(10000)/64)
  float inv = exp2f(-(float)d * 0.20762050593045951f);
  float fr = (float)t * inv;
  float sv, cv;
  sincosf(fr, &sv, &cv);
  cosb[i] = cv; sinb[i] = sv;
}

// ---------- rope apply + scatter; QKV bf16; Q pre-scaled for exp2-domain softmax ----------
__global__ __launch_bounds__(256) void rope_qkv(
    const u16* __restrict__ QKV, const float* __restrict__ cosb, const float* __restrict__ sinb,
    u16* __restrict__ Qb, u16* __restrict__ Kb,
    float* __restrict__ kout, float* __restrict__ vout)
{
  const float QS = 0.08838834764831845f * 1.4426950408889634f;
  const int m = blockIdx.x;                 // b*S + s
  const int b = m >> 11, s = m & 2047;
  const int tid = threadIdx.x;
  const u16* row = QKV + (long)m * NQKV_;
  const int d = tid & 63;
  const float c  = cosb[s*64 + d];
  const float sn = sinb[s*64 + d];
  #pragma unroll
  for (int i = 0; i < 4; i++) {             // 16 q heads
    int hh = (tid + i*256) >> 6;
    float x1 = bf2f(row[hh*128 + d]), x2 = bf2f(row[hh*128 + d + 64]);
    float o1 = x1*c - x2*sn, o2 = x2*c + x1*sn;
    long base = ((long)(b*NQ_ + hh)*S_ + s)*D_;
    Qb[base + d] = f2bf(o1*QS);
    Qb[base + d + 64] = f2bf(o2*QS);
  }
  {                                          // 4 k heads
    int kh = tid >> 6;
    float x1 = bf2f(row[2048 + kh*128 + d]), x2 = bf2f(row[2048 + kh*128 + d + 64]);
    float o1 = x1*c - x2*sn, o2 = x2*c + x1*sn;
    long kb = ((long)(b*NKV_ + kh)*S_ + s)*D_;
    Kb[kb + d] = f2bf(o1);
    Kb[kb + d + 64] = f2bf(o2);
    long ko = ((long)m*NKV_ + kh)*D_;
    kout[ko + d] = o1;
    kout[ko + d + 64] = o2;
  }
  #pragma unroll
  for (int i = 0; i < 2; i++) {              // v passthrough
    int e = tid + i*256;
    vout[(long)m*512 + e] = bf2f(row[2560 + e]);
  }
}

// ---------- GEMM, 8-phase schedule (R12-proven, unchanged) ----------
template<int BM, int BN, int WN, typename OutT>
__global__ __launch_bounds__(512, 2) void gemm8p(
    const u16* __restrict__ A, const u16* __restrict__ Bm,
    const float* __restrict__ bias, OutT* __restrict__ C,
    int M, int N, int K)
{
  constexpr int WM  = 8 / WN;
  constexpr int RW  = (BM/2) / WM;           // per-wave row width within a half
  constexpr int JA  = RW / 16;               // A frags per half
  constexpr int CW  = (BN/2) / WN;           // per-wave col width within a half
  constexpr int JB  = CW / 16;               // B frags per half
  constexpr int ALD = BM/128;                // A loads/thread per half-tile
  constexpr int BLD = BN/128;                // B loads/thread per half-tile
  constexpr int VMC = ALD + BLD;             // newest half-tiles kept in flight
  __shared__ u16 As[2][BM*64];
  __shared__ u16 Bs[2][BN*64];

  const int tid = threadIdx.x;
  const int lane = tid & 63, w = tid >> 6;
  const int r16 = lane & 15, g = lane >> 4;
  const int wrn = w / WN, wcn = w % WN;

  const int gx = gridDim.x;
  const int nwg = gx * gridDim.y;
  const int id = blockIdx.y * gx + blockIdx.x;
  const int cpx = nwg >> 3;
  const int sid = (id & 7) * cpx + (id >> 3);
  const long m0 = (long)(sid / gx) * BM;
  const long n0 = (long)(sid % gx) * BN;

  const u16* Ag = A + m0 * K;
  const u16* Bg = Bm + n0 * K;

  auto stageA = [&](int buf, int h, int k0) {
    #pragma unroll
    for (int i = 0; i < ALD; i++) {
      const int slot = i*512 + tid;
      const int row = h*(BM/2) + (slot >> 3), cg = slot & 7;
      const u16* src = Ag + (long)row*K + k0 + ((cg ^ (row & 7)) * 8);
      gload_lds16(src, &As[buf][h*(BM*32) + slot*8]);
    }
  };
  auto stageB = [&](int buf, int h, int k0) {
    #pragma unroll
    for (int i = 0; i < BLD; i++) {
      const int slot = i*512 + tid;
      const int row = h*(BN/2) + (slot >> 3), cg = slot & 7;
      const u16* src = Bg + (long)row*K + k0 + ((cg ^ (row & 7)) * 8);
      gload_lds16(src, &Bs[buf][h*(BN*32) + slot*8]);
    }
  };

  f32x4 acc[2*JA][2*JB] = {};
  s16x8 Ar[JA][2], Br[JB][2];
  const int nt = K >> 6;

#define PHASE(BUF, MH, NH, RDA, RDB, STMT)                                        \
  do {                                                                            \
    if (RDA) {                                                                    \
      _Pragma("unroll") for (int j = 0; j < JA; j++)                              \
        _Pragma("unroll") for (int kk = 0; kk < 2; kk++) {                        \
          const int R = (MH)*(BM/2) + wrn*RW + j*16 + r16;                        \
          Ar[j][kk] = *(const s16x8*)&As[BUF][R*64 + (((kk*4 + g) ^ (R & 7))*8)]; \
        }                                                                         \
    }                                                                             \
    if (RDB) {                                                                    \
      _Pragma("unroll") for (int jj = 0; jj < JB; jj++)                           \
        _Pragma("unroll") for (int kk = 0; kk < 2; kk++) {                        \
          const int Cc = (NH)*(BN/2) + wcn*CW + jj*16 + r16;                      \
          Br[jj][kk] = *(const s16x8*)&Bs[BUF][Cc*64 + (((kk*4 + g) ^ (Cc & 7))*8)]; \
        }                                                                         \
    }                                                                             \
    STMT;                                                                         \
    __builtin_amdgcn_s_barrier();                                                 \
    asm volatile("s_waitcnt lgkmcnt(0)" ::: "memory");                            \
    __builtin_amdgcn_sched_barrier(0);                                            \
    __builtin_amdgcn_s_setprio(1);                                                \
    _Pragma("unroll") for (int j = 0; j < JA; j++)                                \
      _Pragma("unroll") for (int jj = 0; jj < JB; jj++)                           \
        _Pragma("unroll") for (int kk = 0; kk < 2; kk++)                          \
          acc[(MH)*JA + j][(NH)*JB + jj] =                                        \
            MFMA16(Ar[j][kk], Br[jj][kk], acc[(MH)*JA + j][(NH)*JB + jj]);        \
    __builtin_amdgcn_s_setprio(0);                                                \
    __builtin_amdgcn_s_barrier();                                                 \
  } while (0)

  // prologue: tile0 all 4 halves; tile1's A0 and B1
  stageA(0, 0, 0); stageA(0, 1, 0); stageB(0, 0, 0); stageB(0, 1, 0);
  if (nt > 1) { stageA(1, 0, 64); stageB(1, 1, 64); }

  for (int t = 0; t < nt; t++) {
    const int X = t & 1, Y = X ^ 1;
    if (t == nt - 1) {
      asm volatile("s_waitcnt vmcnt(0)" ::: "memory");
    } else if constexpr (VMC == 4) {
      asm volatile("s_waitcnt vmcnt(4)" ::: "memory");
    } else {
      asm volatile("s_waitcnt vmcnt(3)" ::: "memory");
    }
    __builtin_amdgcn_s_barrier();
    PHASE(X, 0, 0, true,  true,  { if (t+1 < nt) stageA(Y, 1, (t+1)*64); });
    PHASE(X, 0, 1, false, true,  { if (t+1 < nt) stageB(Y, 0, (t+1)*64); });
    PHASE(X, 1, 1, true,  false, { if (t+2 < nt) stageA(X, 0, (t+2)*64); });
    PHASE(X, 1, 0, false, true,  { if (t+2 < nt) stageB(X, 1, (t+2)*64); });
  }
#undef PHASE

  #pragma unroll
  for (int mh = 0; mh < 2; mh++)
    #pragma unroll
    for (int j = 0; j < JA; j++)
      #pragma unroll
      for (int nh = 0; nh < 2; nh++)
        #pragma unroll
        for (int jj = 0; jj < JB; jj++) {
          const int col = nh*(BN/2) + wcn*CW + jj*16 + r16;
          const float bv = bias[n0 + col];
          #pragma unroll
          for (int r = 0; r < 4; r++) {
            const long row = m0 + mh*(BM/2) + wrn*RW + j*16 + g*4 + r;
            const float vv = acc[mh*JA + j][nh*JB + jj][r] + bv;
            if constexpr (sizeof(OutT) == 2)
              C[row * N + n0 + col] = (OutT)f2bf(vv);
            else
              C[row * N + n0 + col] = (OutT)vv;
          }
        }
}

// ---------- flash attention v10: single-buffered K/V, 4+ blocks/CU (TLP-pipelined) ----------
// 512 blocks x 256 threads (4 waves x 32 q-rows = 128-row q-tile). LDS 32KB ->
// 4-5 blocks/CU at launch_bounds(256,4) (112 VGPR < 128 cap). Per step:
// stage -> vmcnt(0)+barrier -> compute -> barrier. Stage latency is hidden by
// co-resident blocks at different phases (m114 wave-level overlap), replacing
// the intra-block double buffer. Compute body identical to v7.
__global__ __launch_bounds__(256, 4) void attn_kernel(
    const u16* __restrict__ Qb, const u16* __restrict__ Kb,
    const u16* __restrict__ Vt, u16* __restrict__ Ob)
{
  __shared__ u16 Ks[64*128];         // [kv][d], granule^(kv&15)
  __shared__ u16 Vs[64*128];         // [d&63][(d>>6)*64+kv], granule^(d2&15)
  const int tid = threadIdx.x;
  const int lane = tid & 63, w = tid >> 6;   // 4 waves
  const int l31 = lane & 31, hi = lane >> 5;
  const int id = blockIdx.x;                 // 512 blocks
  const int bh = id & 31;
  const int b = bh >> 4, h = bh & 15;
  const int p = id >> 5;                     // 0..15
  const int qt = (p < 8) ? (15 - p) : (p - 8);  // long blocks first
  const int kvh = h >> 2;
  const int q0w = qt*128 + w*32;
  const int nt = 2*qt + 2;

  const u16* Qg = Qb + (((long)(b*NQ_ + h))*S_ + q0w)*D_;
  const u16* Kg = Kb + ((long)(b*NKV_ + kvh))*S_*D_;
  const u16* Vg = Vt + ((long)(b*NKV_ + kvh))*D_*S_;

  s16x8 qf[8];
  #pragma unroll
  for (int ks = 0; ks < 8; ks++)
    qf[ks] = *(const s16x8*)&Qg[l31*D_ + ks*16 + hi*8];

  f32x16 po[4] = {};                 // O[q(reg)][d = dt*32 + l31]
  float mrow = -1e30f, lrow = 0.f;

  for (int t = 0; t < nt; t++) {
    const int kv0 = t*64;
    // ---- stage K/V tile (single buffer), pre-swizzled source ----
    #pragma unroll
    for (int i = 0; i < 4; i++) {
      const int c = i*4 + w;                 // 16 chunks of 1KB
      const int G = c*64 + lane;
      const int krow = G >> 4, kcg = G & 15;
      const u16* gk = Kg + (long)(kv0 + krow)*D_ + ((kcg ^ (krow & 15)) * 8);
      gload_lds16(gk, &Ks[c*512]);
      const int o = c*512 + lane*8;
      const int d2 = o >> 7, t16 = (o >> 3) & 15;
      const int gidx = t16 ^ (d2 & 15);
      const int dsr = ((gidx >> 3) << 6) + d2;
      const u16* gv = Vg + (long)dsr*S_ + kv0 + ((gidx & 7) * 8);
      gload_lds16(gv, &Vs[c*512]);
    }
    asm volatile("s_waitcnt vmcnt(0)" ::: "memory");
    __builtin_amdgcn_s_barrier();

    if (kv0 <= q0w + 31) {
      f32x16 sc[2] = {};
      __builtin_amdgcn_s_setprio(1);
      #pragma unroll
      for (int ks = 0; ks < 8; ks++) {
        #pragma unroll
        for (int ct = 0; ct < 2; ct++) {
          const int row = ct*32 + l31;
          s16x8 kf = *(const s16x8*)&Ks[row*128 + ((ks*16 + hi*8) ^ ((row & 15)*8))];
          sc[ct] = MFMA32(kf, qf[ks], sc[ct]);
        }
      }
      __builtin_amdgcn_s_setprio(0);
      if (kv0 + 63 > q0w) {
        const int qrow = q0w + l31;
        #pragma unroll
        for (int ct = 0; ct < 2; ct++)
          #pragma unroll
          for (int r = 0; r < 16; r++) {
            int kv = kv0 + ct*32 + (r & 3) + 8*(r >> 2) + 4*hi;
            if (kv > qrow) sc[ct][r] = -3.0e38f;
          }
      }
      float pm = sc[0][0];
      #pragma unroll
      for (int ct = 0; ct < 2; ct++)
        #pragma unroll
        for (int r = 0; r < 16; r++) pm = fmaxf(pm, sc[ct][r]);
      pm = fmaxf(pm, __shfl_xor(pm, 32, 64));
      if (!__all(pm - mrow <= 8.0f)) {       // defer-max (T13)
        float mn = fmaxf(mrow, pm);
        float fr = exp2f(mrow - mn);
        mrow = mn;
        lrow *= fr;
        #pragma unroll
        for (int r = 0; r < 16; r++) {
          float frv = __shfl(fr, (r & 3) + 8*(r >> 2) + 4*hi, 64);
          #pragma unroll
          for (int dt = 0; dt < 4; dt++) po[dt][r] *= frv;
        }
      }
      float ps = 0.f;
      #pragma unroll
      for (int ct = 0; ct < 2; ct++)
        #pragma unroll
        for (int r = 0; r < 16; r++) {
          float pv = exp2f(sc[ct][r] - mrow);
          sc[ct][r] = pv;
          ps += pv;
        }
      ps += __shfl_xor(ps, 32, 64);
      lrow += ps;
      unsigned mw[2][8];
      #pragma unroll
      for (int ct = 0; ct < 2; ct++)
        #pragma unroll
        for (int wd = 0; wd < 8; wd++)
          mw[ct][wd] = cvtpk(sc[ct][2*wd], sc[ct][2*wd + 1]);
      s16x8 pa[4];
      #pragma unroll
      for (int ct = 0; ct < 2; ct++)
        #pragma unroll
        for (int pp = 0; pp < 2; pp++) {
          unsigned a0 = mw[ct][4*pp + 0], b0 = mw[ct][4*pp + 2];
          unsigned a1 = mw[ct][4*pp + 1], b1 = mw[ct][4*pp + 3];
          plswap(a0, b0);
          plswap(a1, b1);
          union { unsigned u[4]; s16x8 v; } pu;
          pu.u[0] = a0; pu.u[1] = a1; pu.u[2] = b0; pu.u[3] = b1;
          pa[ct*2 + pp] = pu.v;
        }
      __builtin_amdgcn_s_setprio(1);
      #pragma unroll
      for (int ks2 = 0; ks2 < 4; ks2++)
        #pragma unroll
        for (int dt = 0; dt < 4; dt++) {
          const int d = dt*32 + l31, d2 = d & 63;
          const int gidx = ((d >> 6) << 3) + ks2*2 + hi;
          s16x8 vf = *(const s16x8*)&Vs[d2*128 + ((gidx ^ (d2 & 15)) * 8)];
          po[dt] = MFMA32(pa[ks2], vf, po[dt]);
        }
      __builtin_amdgcn_s_setprio(0);
    }
    __builtin_amdgcn_s_barrier();
  }

  float inv = 1.0f / lrow;
  #pragma unroll
  for (int r = 0; r < 16; r++) {
    const int qr = (r & 3) + 8*(r >> 2) + 4*hi;
    float invq = __shfl(inv, qr, 64);
    const long q = (long)q0w + qr;
    #pragma unroll
    for (int dt = 0; dt < 4; dt++)
      Ob[((long)b*S_ + q)*H_ + h*D_ + dt*32 + l31] = f2bf(po[dt][r]*invq);
  }
}

// ---------- launcher ----------
extern "C" void kernel_launch(void* const* d_in, const int* in_sizes, int n_in,
                              void* d_out, int out_size, void* d_ws, size_t ws_size,
                              hipStream_t stream) {
  const float* hs = (const float*)d_in[0];
  const float* Wq = (const float*)d_in[1];
  const float* bq = (const float*)d_in[2];
  const float* Wk = (const float*)d_in[3];
  const float* bk = (const float*)d_in[4];
  const float* Wv = (const float*)d_in[5];
  const float* bv = (const float*)d_in[6];
  const float* Wc = (const float*)d_in[7];
  const float* bc = (const float*)d_in[8];

  float* out  = (float*)d_out;                  // (B,S,H)
  float* kout = out + (long)M_*H_;              // (B,S,NKV,D)
  float* vout = kout + (long)M_*NKV_*D_;        // (B,S,NKV,D)

  char* ws = (char*)d_ws;
  u16*  Xbf   = (u16*)ws;                                   // [4096][2048]
  u16*  Wqkvt = Xbf + (long)M_*H_;                          // [3072][2048]
  u16*  Wct   = Wqkvt + (long)NQKV_*H_;                     // [2048][2048]
  float* bqkv = (float*)(Wct + (long)H_*H_);                // [3072]
  u16*  QKV   = (u16*)(bqkv + NQKV_);                       // [4096][3072] bf16
  float* cosb = (float*)(QKV + (long)M_*NQKV_);             // [2048][64]
  float* sinb = cosb + S_*64;
  u16*  Qbf   = (u16*)(sinb + S_*64);                       // [B][NQ][S][D] (pre-scaled)
  u16*  Kbf   = Qbf + (long)B_*NQ_*S_*D_;                   // [B][NKV][S][D]
  u16*  Vtb   = Kbf + (long)B_*NKV_*S_*D_;                  // [B][NKV][D][S]
  u16*  Obf   = Vtb + (long)B_*NKV_*D_*S_;                  // [4096][2048]

  cvt_x<<<2048, 256, 0, stream>>>(hs, Xbf, (long)M_*H_/4);
  wtrans<<<dim3(64,64), dim3(32,8), 0, stream>>>(Wq, Wqkvt, 2048, 2048);
  wtrans<<<dim3(16,64), dim3(32,8), 0, stream>>>(Wk, Wqkvt + 2048L*2048, 512, 2048);
  wtrans<<<dim3(16,64), dim3(32,8), 0, stream>>>(Wv, Wqkvt + 2560L*2048, 512, 2048);
  wtrans<<<dim3(64,64), dim3(32,8), 0, stream>>>(Wc, Wct, 2048, 2048);
  concat_bias<<<12, 256, 0, stream>>>(bq, bk, bv, bqkv);
  rope_tab<<<512, 256, 0, stream>>>(cosb, sinb);

  // QKV: BM=128, BN=384 -> grid 8x32 = 256 blocks (full machine)
  gemm8p<128, 384, 4, u16><<<dim3(NQKV_/384, M_/128), 512, 0, stream>>>(
      Xbf, Wqkvt, bqkv, QKV, M_, NQKV_, H_);
  rope_qkv<<<M_, 256, 0, stream>>>(QKV, cosb, sinb, Qbf, Kbf, kout, vout);
  vtrans<<<dim3(S_/32, D_/32, B_*NKV_), dim3(32,8), 0, stream>>>(QKV, Vtb);
  attn_kernel<<<dim3(512), 256, 0, stream>>>(Qbf, Kbf, Vtb, Obf);
  // out-proj: BM=256, BN=128 -> grid 16x16 = 256 blocks
  gemm8p<256, 128, 2, float><<<dim3(H_/128, M_/256), 512, 0, stream>>>(
      Obf, Wct, bc, out, M_, H_, H_);
}

// Round 17
// 219.623 us; speedup vs baseline: 1.7621x; 1.7621x over previous
//
#include <hip/hip_runtime.h>
#include <math.h>

typedef unsigned short u16;
typedef __attribute__((ext_vector_type(8))) short s16x8;
typedef __attribute__((ext_vector_type(4))) float f32x4;
typedef __attribute__((ext_vector_type(16))) float f32x16;
typedef unsigned u32x2u __attribute__((ext_vector_type(2)));

// ---------- constants ----------
#define B_  2
#define S_  2048
#define H_  2048
#define D_  128
#define NQ_ 16
#define NKV_ 4
#define M_  (B_*S_)        // 4096
#define NQKV_ 3072         // NQ*D + 2*NKV*D

#define MFMA16(a,b,c) __builtin_amdgcn_mfma_f32_16x16x32_bf16(a,b,c,0,0,0)
#define MFMA32(a,b,c) __builtin_amdgcn_mfma_f32_32x32x16_bf16(a,b,c,0,0,0)

__device__ __forceinline__ u16 f2bf(float x) {
  union { float f; unsigned u; } v; v.f = x;
  unsigned r = v.u + 0x7fffu + ((v.u >> 16) & 1u);
  return (u16)(r >> 16);
}
__device__ __forceinline__ float bf2f(u16 x) {
  union { unsigned u; float f; } v; v.u = ((unsigned)x) << 16;
  return v.f;
}

__device__ __forceinline__ unsigned cvtpk(float lo, float hi) {
  unsigned r;
  asm("v_cvt_pk_bf16_f32 %0, %1, %2" : "=v"(r) : "v"(lo), "v"(hi));
  return r;
}

// T12: exchange half-waves: x' = {x.row0, y.row0}, y' = {x.row1, y.row1}
__device__ __forceinline__ void plswap(unsigned &x, unsigned &y) {
#if __has_builtin(__builtin_amdgcn_permlane32_swap)
  u32x2u r = __builtin_amdgcn_permlane32_swap(x, y, false, false);
  x = r[0]; y = r[1];
#else
  const bool hb = (threadIdx.x & 32) != 0;
  unsigned ex = (unsigned)__shfl_xor((int)x, 32, 64);
  unsigned ey = (unsigned)__shfl_xor((int)y, 32, 64);
  unsigned nx = hb ? ey : x;
  unsigned ny = hb ? y : ex;
  x = nx; y = ny;
#endif
}

__device__ __forceinline__ void gload_lds16(const u16* src, u16* dst) {
  __builtin_amdgcn_global_load_lds(
      (const __attribute__((address_space(1))) unsigned int*)src,
      (__attribute__((address_space(3))) unsigned int*)dst, 16, 0, 0);
}

// ---------- elementwise fp32 -> bf16 ----------
__global__ __launch_bounds__(256) void cvt_x(const float* __restrict__ X, u16* __restrict__ Xb, long n4) {
  const f32x4* X4 = (const f32x4*)X;
  for (long i = (long)blockIdx.x*256 + threadIdx.x; i < n4; i += (long)gridDim.x*256) {
    f32x4 v = X4[i];
    union { u16 u[4]; unsigned long long ll; } p;
    p.u[0] = f2bf(v[0]); p.u[1] = f2bf(v[1]); p.u[2] = f2bf(v[2]); p.u[3] = f2bf(v[3]);
    ((unsigned long long*)Xb)[i] = p.ll;
  }
}

// ---------- transpose + convert: W [K][N] fp32 -> Wt [N][K] bf16 ----------
__global__ __launch_bounds__(256) void wtrans(const float* __restrict__ W, u16* __restrict__ Wt,
                                              int N, int K) {
  __shared__ float t[32][33];
  const int n0 = blockIdx.x*32, k0 = blockIdx.y*32;
  const int tx = threadIdx.x, ty = threadIdx.y;   // (32,8)
  #pragma unroll
  for (int i = 0; i < 32; i += 8) t[ty+i][tx] = W[(long)(k0+ty+i)*N + n0 + tx];
  __syncthreads();
  #pragma unroll
  for (int i = 0; i < 32; i += 8) Wt[(long)(n0+ty+i)*K + k0 + tx] = f2bf(t[tx][ty+i]);
}

// ---------- V transpose: QKV bf16 v-part -> Vt bf16 [B][NKV][D][S] ----------
__global__ __launch_bounds__(256) void vtrans(const u16* __restrict__ QKV, u16* __restrict__ Vt) {
  __shared__ u16 t[32][33];
  const int bk = blockIdx.z;            // b*4+kvh
  const int s0 = blockIdx.x*32, d0 = blockIdx.y*32;
  const int tx = threadIdx.x, ty = threadIdx.y;
  const int b = bk >> 2, kvh = bk & 3;
  #pragma unroll
  for (int i = 0; i < 32; i += 8)
    t[ty+i][tx] = QKV[(long)(b*S_ + s0+ty+i)*NQKV_ + 2560 + kvh*128 + d0 + tx];
  __syncthreads();
  #pragma unroll
  for (int i = 0; i < 32; i += 8)
    Vt[((long)bk*D_ + d0+ty+i)*S_ + s0 + tx] = t[tx][ty+i];
}

// ---------- bias concat ----------
__global__ void concat_bias(const float* bq, const float* bk, const float* bv, float* bqkv) {
  int i = blockIdx.x*256 + threadIdx.x;
  if (i < NQKV_)
    bqkv[i] = (i < 2048) ? bq[i] : ((i < 2560) ? bk[i-2048] : bv[i-2560]);
}

// ---------- rope tables (exp2 instead of powf) ----------
__global__ void rope_tab(float* __restrict__ cosb, float* __restrict__ sinb) {
  int i = blockIdx.x*256 + threadIdx.x;   // 2048*64
  int t = i >> 6, d = i & 63;
  // 10000^(-d/64) = exp2(-d * log2(10000)/64)
  float inv = exp2f(-(float)d * 0.20762050593045951f);
  float fr = (float)t * inv;
  float sv, cv;
  sincosf(fr, &sv, &cv);
  cosb[i] = cv; sinb[i] = sv;
}

// ---------- rope apply + scatter; QKV bf16; Q pre-scaled for exp2-domain softmax ----------
__global__ __launch_bounds__(256) void rope_qkv(
    const u16* __restrict__ QKV, const float* __restrict__ cosb, const float* __restrict__ sinb,
    u16* __restrict__ Qb, u16* __restrict__ Kb,
    float* __restrict__ kout, float* __restrict__ vout)
{
  const float QS = 0.08838834764831845f * 1.4426950408889634f;
  const int m = blockIdx.x;                 // b*S + s
  const int b = m >> 11, s = m & 2047;
  const int tid = threadIdx.x;
  const u16* row = QKV + (long)m * NQKV_;
  const int d = tid & 63;
  const float c  = cosb[s*64 + d];
  const float sn = sinb[s*64 + d];
  #pragma unroll
  for (int i = 0; i < 4; i++) {             // 16 q heads
    int hh = (tid + i*256) >> 6;
    float x1 = bf2f(row[hh*128 + d]), x2 = bf2f(row[hh*128 + d + 64]);
    float o1 = x1*c - x2*sn, o2 = x2*c + x1*sn;
    long base = ((long)(b*NQ_ + hh)*S_ + s)*D_;
    Qb[base + d] = f2bf(o1*QS);
    Qb[base + d + 64] = f2bf(o2*QS);
  }
  {                                          // 4 k heads
    int kh = tid >> 6;
    float x1 = bf2f(row[2048 + kh*128 + d]), x2 = bf2f(row[2048 + kh*128 + d + 64]);
    float o1 = x1*c - x2*sn, o2 = x2*c + x1*sn;
    long kb = ((long)(b*NKV_ + kh)*S_ + s)*D_;
    Kb[kb + d] = f2bf(o1);
    Kb[kb + d + 64] = f2bf(o2);
    long ko = ((long)m*NKV_ + kh)*D_;
    kout[ko + d] = o1;
    kout[ko + d + 64] = o2;
  }
  #pragma unroll
  for (int i = 0; i < 2; i++) {              // v passthrough
    int e = tid + i*256;
    vout[(long)m*512 + e] = bf2f(row[2560 + e]);
  }
}

// ---------- GEMM, 8-phase schedule (R12-proven, unchanged) ----------
template<int BM, int BN, int WN, typename OutT>
__global__ __launch_bounds__(512, 2) void gemm8p(
    const u16* __restrict__ A, const u16* __restrict__ Bm,
    const float* __restrict__ bias, OutT* __restrict__ C,
    int M, int N, int K)
{
  constexpr int WM  = 8 / WN;
  constexpr int RW  = (BM/2) / WM;           // per-wave row width within a half
  constexpr int JA  = RW / 16;               // A frags per half
  constexpr int CW  = (BN/2) / WN;           // per-wave col width within a half
  constexpr int JB  = CW / 16;               // B frags per half
  constexpr int ALD = BM/128;                // A loads/thread per half-tile
  constexpr int BLD = BN/128;                // B loads/thread per half-tile
  constexpr int VMC = ALD + BLD;             // newest half-tiles kept in flight
  __shared__ u16 As[2][BM*64];
  __shared__ u16 Bs[2][BN*64];

  const int tid = threadIdx.x;
  const int lane = tid & 63, w = tid >> 6;
  const int r16 = lane & 15, g = lane >> 4;
  const int wrn = w / WN, wcn = w % WN;

  const int gx = gridDim.x;
  const int nwg = gx * gridDim.y;
  const int id = blockIdx.y * gx + blockIdx.x;
  const int cpx = nwg >> 3;
  const int sid = (id & 7) * cpx + (id >> 3);
  const long m0 = (long)(sid / gx) * BM;
  const long n0 = (long)(sid % gx) * BN;

  const u16* Ag = A + m0 * K;
  const u16* Bg = Bm + n0 * K;

  auto stageA = [&](int buf, int h, int k0) {
    #pragma unroll
    for (int i = 0; i < ALD; i++) {
      const int slot = i*512 + tid;
      const int row = h*(BM/2) + (slot >> 3), cg = slot & 7;
      const u16* src = Ag + (long)row*K + k0 + ((cg ^ (row & 7)) * 8);
      gload_lds16(src, &As[buf][h*(BM*32) + slot*8]);
    }
  };
  auto stageB = [&](int buf, int h, int k0) {
    #pragma unroll
    for (int i = 0; i < BLD; i++) {
      const int slot = i*512 + tid;
      const int row = h*(BN/2) + (slot >> 3), cg = slot & 7;
      const u16* src = Bg + (long)row*K + k0 + ((cg ^ (row & 7)) * 8);
      gload_lds16(src, &Bs[buf][h*(BN*32) + slot*8]);
    }
  };

  f32x4 acc[2*JA][2*JB] = {};
  s16x8 Ar[JA][2], Br[JB][2];
  const int nt = K >> 6;

#define PHASE(BUF, MH, NH, RDA, RDB, STMT)                                        \
  do {                                                                            \
    if (RDA) {                                                                    \
      _Pragma("unroll") for (int j = 0; j < JA; j++)                              \
        _Pragma("unroll") for (int kk = 0; kk < 2; kk++) {                        \
          const int R = (MH)*(BM/2) + wrn*RW + j*16 + r16;                        \
          Ar[j][kk] = *(const s16x8*)&As[BUF][R*64 + (((kk*4 + g) ^ (R & 7))*8)]; \
        }                                                                         \
    }                                                                             \
    if (RDB) {                                                                    \
      _Pragma("unroll") for (int jj = 0; jj < JB; jj++)                           \
        _Pragma("unroll") for (int kk = 0; kk < 2; kk++) {                        \
          const int Cc = (NH)*(BN/2) + wcn*CW + jj*16 + r16;                      \
          Br[jj][kk] = *(const s16x8*)&Bs[BUF][Cc*64 + (((kk*4 + g) ^ (Cc & 7))*8)]; \
        }                                                                         \
    }                                                                             \
    STMT;                                                                         \
    __builtin_amdgcn_s_barrier();                                                 \
    asm volatile("s_waitcnt lgkmcnt(0)" ::: "memory");                            \
    __builtin_amdgcn_sched_barrier(0);                                            \
    __builtin_amdgcn_s_setprio(1);                                                \
    _Pragma("unroll") for (int j = 0; j < JA; j++)                                \
      _Pragma("unroll") for (int jj = 0; jj < JB; jj++)                           \
        _Pragma("unroll") for (int kk = 0; kk < 2; kk++)                          \
          acc[(MH)*JA + j][(NH)*JB + jj] =                                        \
            MFMA16(Ar[j][kk], Br[jj][kk], acc[(MH)*JA + j][(NH)*JB + jj]);        \
    __builtin_amdgcn_s_setprio(0);                                                \
    __builtin_amdgcn_s_barrier();                                                 \
  } while (0)

  // prologue: tile0 all 4 halves; tile1's A0 and B1
  stageA(0, 0, 0); stageA(0, 1, 0); stageB(0, 0, 0); stageB(0, 1, 0);
  if (nt > 1) { stageA(1, 0, 64); stageB(1, 1, 64); }

  for (int t = 0; t < nt; t++) {
    const int X = t & 1, Y = X ^ 1;
    if (t == nt - 1) {
      asm volatile("s_waitcnt vmcnt(0)" ::: "memory");
    } else if constexpr (VMC == 4) {
      asm volatile("s_waitcnt vmcnt(4)" ::: "memory");
    } else {
      asm volatile("s_waitcnt vmcnt(3)" ::: "memory");
    }
    __builtin_amdgcn_s_barrier();
    PHASE(X, 0, 0, true,  true,  { if (t+1 < nt) stageA(Y, 1, (t+1)*64); });
    PHASE(X, 0, 1, false, true,  { if (t+1 < nt) stageB(Y, 0, (t+1)*64); });
    PHASE(X, 1, 1, true,  false, { if (t+2 < nt) stageA(X, 0, (t+2)*64); });
    PHASE(X, 1, 0, false, true,  { if (t+2 < nt) stageB(X, 1, (t+2)*64); });
  }
#undef PHASE

  #pragma unroll
  for (int mh = 0; mh < 2; mh++)
    #pragma unroll
    for (int j = 0; j < JA; j++)
      #pragma unroll
      for (int nh = 0; nh < 2; nh++)
        #pragma unroll
        for (int jj = 0; jj < JB; jj++) {
          const int col = nh*(BN/2) + wcn*CW + jj*16 + r16;
          const float bv = bias[n0 + col];
          #pragma unroll
          for (int r = 0; r < 4; r++) {
            const long row = m0 + mh*(BM/2) + wrn*RW + j*16 + g*4 + r;
            const float vv = acc[mh*JA + j][nh*JB + jj][r] + bv;
            if constexpr (sizeof(OutT) == 2)
              C[row * N + n0 + col] = (OutT)f2bf(vv);
            else
              C[row * N + n0 + col] = (OutT)vv;
          }
        }
}

// ---------- flash attention v10b: single-buffered K/V at launch_bounds(256,2) ----------
// 512 blocks x 256 threads (4 waves x 32 q-rows). LDS 32KB; VGPR ~112 (no cap ->
// no spill; R16's (256,4) forced 64 VGPR and spilled). Runtime occupancy:
// min(LDS 5, VGPR 4) = 4 blocks/CU = 4 waves/SIMD — double R15's TLP. Per step:
// stage -> vmcnt(0)+barrier -> compute -> barrier; co-resident blocks at
// different phases hide the serial stage latency (m114). Body identical to v7.
__global__ __launch_bounds__(256, 2) void attn_kernel(
    const u16* __restrict__ Qb, const u16* __restrict__ Kb,
    const u16* __restrict__ Vt, u16* __restrict__ Ob)
{
  __shared__ u16 Ks[64*128];         // [kv][d], granule^(kv&15)
  __shared__ u16 Vs[64*128];         // [d&63][(d>>6)*64+kv], granule^(d2&15)
  const int tid = threadIdx.x;
  const int lane = tid & 63, w = tid >> 6;   // 4 waves
  const int l31 = lane & 31, hi = lane >> 5;
  const int id = blockIdx.x;                 // 512 blocks
  const int bh = id & 31;
  const int b = bh >> 4, h = bh & 15;
  const int p = id >> 5;                     // 0..15
  const int qt = (p < 8) ? (15 - p) : (p - 8);  // long blocks first
  const int kvh = h >> 2;
  const int q0w = qt*128 + w*32;
  const int nt = 2*qt + 2;

  const u16* Qg = Qb + (((long)(b*NQ_ + h))*S_ + q0w)*D_;
  const u16* Kg = Kb + ((long)(b*NKV_ + kvh))*S_*D_;
  const u16* Vg = Vt + ((long)(b*NKV_ + kvh))*D_*S_;

  s16x8 qf[8];
  #pragma unroll
  for (int ks = 0; ks < 8; ks++)
    qf[ks] = *(const s16x8*)&Qg[l31*D_ + ks*16 + hi*8];

  f32x16 po[4] = {};                 // O[q(reg)][d = dt*32 + l31]
  float mrow = -1e30f, lrow = 0.f;

  for (int t = 0; t < nt; t++) {
    const int kv0 = t*64;
    // ---- stage K/V tile (single buffer), pre-swizzled source ----
    #pragma unroll
    for (int i = 0; i < 4; i++) {
      const int c = i*4 + w;                 // 16 chunks of 1KB
      const int G = c*64 + lane;
      const int krow = G >> 4, kcg = G & 15;
      const u16* gk = Kg + (long)(kv0 + krow)*D_ + ((kcg ^ (krow & 15)) * 8);
      gload_lds16(gk, &Ks[c*512]);
      const int o = c*512 + lane*8;
      const int d2 = o >> 7, t16 = (o >> 3) & 15;
      const int gidx = t16 ^ (d2 & 15);
      const int dsr = ((gidx >> 3) << 6) + d2;
      const u16* gv = Vg + (long)dsr*S_ + kv0 + ((gidx & 7) * 8);
      gload_lds16(gv, &Vs[c*512]);
    }
    asm volatile("s_waitcnt vmcnt(0)" ::: "memory");
    __builtin_amdgcn_s_barrier();

    if (kv0 <= q0w + 31) {
      f32x16 sc[2] = {};
      __builtin_amdgcn_s_setprio(1);
      #pragma unroll
      for (int ks = 0; ks < 8; ks++) {
        #pragma unroll
        for (int ct = 0; ct < 2; ct++) {
          const int row = ct*32 + l31;
          s16x8 kf = *(const s16x8*)&Ks[row*128 + ((ks*16 + hi*8) ^ ((row & 15)*8))];
          sc[ct] = MFMA32(kf, qf[ks], sc[ct]);
        }
      }
      __builtin_amdgcn_s_setprio(0);
      if (kv0 + 63 > q0w) {
        const int qrow = q0w + l31;
        #pragma unroll
        for (int ct = 0; ct < 2; ct++)
          #pragma unroll
          for (int r = 0; r < 16; r++) {
            int kv = kv0 + ct*32 + (r & 3) + 8*(r >> 2) + 4*hi;
            if (kv > qrow) sc[ct][r] = -3.0e38f;
          }
      }
      float pm = sc[0][0];
      #pragma unroll
      for (int ct = 0; ct < 2; ct++)
        #pragma unroll
        for (int r = 0; r < 16; r++) pm = fmaxf(pm, sc[ct][r]);
      pm = fmaxf(pm, __shfl_xor(pm, 32, 64));
      if (!__all(pm - mrow <= 8.0f)) {       // defer-max (T13)
        float mn = fmaxf(mrow, pm);
        float fr = exp2f(mrow - mn);
        mrow = mn;
        lrow *= fr;
        #pragma unroll
        for (int r = 0; r < 16; r++) {
          float frv = __shfl(fr, (r & 3) + 8*(r >> 2) + 4*hi, 64);
          #pragma unroll
          for (int dt = 0; dt < 4; dt++) po[dt][r] *= frv;
        }
      }
      float ps = 0.f;
      #pragma unroll
      for (int ct = 0; ct < 2; ct++)
        #pragma unroll
        for (int r = 0; r < 16; r++) {
          float pv = exp2f(sc[ct][r] - mrow);
          sc[ct][r] = pv;
          ps += pv;
        }
      ps += __shfl_xor(ps, 32, 64);
      lrow += ps;
      unsigned mw[2][8];
      #pragma unroll
      for (int ct = 0; ct < 2; ct++)
        #pragma unroll
        for (int wd = 0; wd < 8; wd++)
          mw[ct][wd] = cvtpk(sc[ct][2*wd], sc[ct][2*wd + 1]);
      s16x8 pa[4];
      #pragma unroll
      for (int ct = 0; ct < 2; ct++)
        #pragma unroll
        for (int pp = 0; pp < 2; pp++) {
          unsigned a0 = mw[ct][4*pp + 0], b0 = mw[ct][4*pp + 2];
          unsigned a1 = mw[ct][4*pp + 1], b1 = mw[ct][4*pp + 3];
          plswap(a0, b0);
          plswap(a1, b1);
          union { unsigned u[4]; s16x8 v; } pu;
          pu.u[0] = a0; pu.u[1] = a1; pu.u[2] = b0; pu.u[3] = b1;
          pa[ct*2 + pp] = pu.v;
        }
      __builtin_amdgcn_s_setprio(1);
      #pragma unroll
      for (int ks2 = 0; ks2 < 4; ks2++)
        #pragma unroll
        for (int dt = 0; dt < 4; dt++) {
          const int d = dt*32 + l31, d2 = d & 63;
          const int gidx = ((d >> 6) << 3) + ks2*2 + hi;
          s16x8 vf = *(const s16x8*)&Vs[d2*128 + ((gidx ^ (d2 & 15)) * 8)];
          po[dt] = MFMA32(pa[ks2], vf, po[dt]);
        }
      __builtin_amdgcn_s_setprio(0);
    }
    __builtin_amdgcn_s_barrier();
  }

  float inv = 1.0f / lrow;
  #pragma unroll
  for (int r = 0; r < 16; r++) {
    const int qr = (r & 3) + 8*(r >> 2) + 4*hi;
    float invq = __shfl(inv, qr, 64);
    const long q = (long)q0w + qr;
    #pragma unroll
    for (int dt = 0; dt < 4; dt++)
      Ob[((long)b*S_ + q)*H_ + h*D_ + dt*32 + l31] = f2bf(po[dt][r]*invq);
  }
}

// ---------- launcher ----------
extern "C" void kernel_launch(void* const* d_in, const int* in_sizes, int n_in,
                              void* d_out, int out_size, void* d_ws, size_t ws_size,
                              hipStream_t stream) {
  const float* hs = (const float*)d_in[0];
  const float* Wq = (const float*)d_in[1];
  const float* bq = (const float*)d_in[2];
  const float* Wk = (const float*)d_in[3];
  const float* bk = (const float*)d_in[4];
  const float* Wv = (const float*)d_in[5];
  const float* bv = (const float*)d_in[6];
  const float* Wc = (const float*)d_in[7];
  const float* bc = (const float*)d_in[8];

  float* out  = (float*)d_out;                  // (B,S,H)
  float* kout = out + (long)M_*H_;              // (B,S,NKV,D)
  float* vout = kout + (long)M_*NKV_*D_;        // (B,S,NKV,D)

  char* ws = (char*)d_ws;
  u16*  Xbf   = (u16*)ws;                                   // [4096][2048]
  u16*  Wqkvt = Xbf + (long)M_*H_;                          // [3072][2048]
  u16*  Wct   = Wqkvt + (long)NQKV_*H_;                     // [2048][2048]
  float* bqkv = (float*)(Wct + (long)H_*H_);                // [3072]
  u16*  QKV   = (u16*)(bqkv + NQKV_);                       // [4096][3072] bf16
  float* cosb = (float*)(QKV + (long)M_*NQKV_);             // [2048][64]
  float* sinb = cosb + S_*64;
  u16*  Qbf   = (u16*)(sinb + S_*64);                       // [B][NQ][S][D] (pre-scaled)
  u16*  Kbf   = Qbf + (long)B_*NQ_*S_*D_;                   // [B][NKV][S][D]
  u16*  Vtb   = Kbf + (long)B_*NKV_*S_*D_;                  // [B][NKV][D][S]
  u16*  Obf   = Vtb + (long)B_*NKV_*D_*S_;                  // [4096][2048]

  cvt_x<<<2048, 256, 0, stream>>>(hs, Xbf, (long)M_*H_/4);
  wtrans<<<dim3(64,64), dim3(32,8), 0, stream>>>(Wq, Wqkvt, 2048, 2048);
  wtrans<<<dim3(16,64), dim3(32,8), 0, stream>>>(Wk, Wqkvt + 2048L*2048, 512, 2048);
  wtrans<<<dim3(16,64), dim3(32,8), 0, stream>>>(Wv, Wqkvt + 2560L*2048, 512, 2048);
  wtrans<<<dim3(64,64), dim3(32,8), 0, stream>>>(Wc, Wct, 2048, 2048);
  concat_bias<<<12, 256, 0, stream>>>(bq, bk, bv, bqkv);
  rope_tab<<<512, 256, 0, stream>>>(cosb, sinb);

  // QKV: BM=128, BN=384 -> grid 8x32 = 256 blocks (full machine)
  gemm8p<128, 384, 4, u16><<<dim3(NQKV_/384, M_/128), 512, 0, stream>>>(
      Xbf, Wqkvt, bqkv, QKV, M_, NQKV_, H_);
  rope_qkv<<<M_, 256, 0, stream>>>(QKV, cosb, sinb, Qbf, Kbf, kout, vout);
  vtrans<<<dim3(S_/32, D_/32, B_*NKV_), dim3(32,8), 0, stream>>>(QKV, Vtb);
  attn_kernel<<<dim3(512), 256, 0, stream>>>(Qbf, Kbf, Vtb, Obf);
  // out-proj: BM=256, BN=128 -> grid 16x16 = 256 blocks
  gemm8p<256, 128, 2, float><<<dim3(H_/128, M_/256), 512, 0, stream>>>(
      Obf, Wct, bc, out, M_, H_, H_);
}

// Round 18
// 212.354 us; speedup vs baseline: 1.8224x; 1.0342x over previous
//
#include <hip/hip_runtime.h>
#include <math.h>

typedef unsigned short u16;
typedef __attribute__((ext_vector_type(8))) short s16x8;
typedef __attribute__((ext_vector_type(4))) float f32x4;
typedef __attribute__((ext_vector_type(16))) float f32x16;
typedef unsigned u32x2u __attribute__((ext_vector_type(2)));

// ---------- constants ----------
#define B_  2
#define S_  2048
#define H_  2048
#define D_  128
#define NQ_ 16
#define NKV_ 4
#define M_  (B_*S_)        // 4096
#define NQKV_ 3072         // NQ*D + 2*NKV*D

#define MFMA16(a,b,c) __builtin_amdgcn_mfma_f32_16x16x32_bf16(a,b,c,0,0,0)
#define MFMA32(a,b,c) __builtin_amdgcn_mfma_f32_32x32x16_bf16(a,b,c,0,0,0)

__device__ __forceinline__ u16 f2bf(float x) {
  union { float f; unsigned u; } v; v.f = x;
  unsigned r = v.u + 0x7fffu + ((v.u >> 16) & 1u);
  return (u16)(r >> 16);
}
__device__ __forceinline__ float bf2f(u16 x) {
  union { unsigned u; float f; } v; v.u = ((unsigned)x) << 16;
  return v.f;
}

__device__ __forceinline__ unsigned cvtpk(float lo, float hi) {
  unsigned r;
  asm("v_cvt_pk_bf16_f32 %0, %1, %2" : "=v"(r) : "v"(lo), "v"(hi));
  return r;
}

// T12: exchange half-waves: x' = {x.row0, y.row0}, y' = {x.row1, y.row1}
__device__ __forceinline__ void plswap(unsigned &x, unsigned &y) {
#if __has_builtin(__builtin_amdgcn_permlane32_swap)
  u32x2u r = __builtin_amdgcn_permlane32_swap(x, y, false, false);
  x = r[0]; y = r[1];
#else
  const bool hb = (threadIdx.x & 32) != 0;
  unsigned ex = (unsigned)__shfl_xor((int)x, 32, 64);
  unsigned ey = (unsigned)__shfl_xor((int)y, 32, 64);
  unsigned nx = hb ? ey : x;
  unsigned ny = hb ? y : ex;
  x = nx; y = ny;
#endif
}

__device__ __forceinline__ void gload_lds16(const u16* src, u16* dst) {
  __builtin_amdgcn_global_load_lds(
      (const __attribute__((address_space(1))) unsigned int*)src,
      (__attribute__((address_space(3))) unsigned int*)dst, 16, 0, 0);
}

// ---------- elementwise fp32 -> bf16 ----------
__global__ __launch_bounds__(256) void cvt_x(const float* __restrict__ X, u16* __restrict__ Xb, long n4) {
  const f32x4* X4 = (const f32x4*)X;
  for (long i = (long)blockIdx.x*256 + threadIdx.x; i < n4; i += (long)gridDim.x*256) {
    f32x4 v = X4[i];
    union { u16 u[4]; unsigned long long ll; } p;
    p.u[0] = f2bf(v[0]); p.u[1] = f2bf(v[1]); p.u[2] = f2bf(v[2]); p.u[3] = f2bf(v[3]);
    ((unsigned long long*)Xb)[i] = p.ll;
  }
}

// ---------- transpose + convert: W [K][N] fp32 -> Wt [N][K] bf16 ----------
__global__ __launch_bounds__(256) void wtrans(const float* __restrict__ W, u16* __restrict__ Wt,
                                              int N, int K) {
  __shared__ float t[32][33];
  const int n0 = blockIdx.x*32, k0 = blockIdx.y*32;
  const int tx = threadIdx.x, ty = threadIdx.y;   // (32,8)
  #pragma unroll
  for (int i = 0; i < 32; i += 8) t[ty+i][tx] = W[(long)(k0+ty+i)*N + n0 + tx];
  __syncthreads();
  #pragma unroll
  for (int i = 0; i < 32; i += 8) Wt[(long)(n0+ty+i)*K + k0 + tx] = f2bf(t[tx][ty+i]);
}

// ---------- V transpose: QKV bf16 v-part -> Vt bf16 [B][NKV][D][S] ----------
__global__ __launch_bounds__(256) void vtrans(const u16* __restrict__ QKV, u16* __restrict__ Vt) {
  __shared__ u16 t[32][33];
  const int bk = blockIdx.z;            // b*4+kvh
  const int s0 = blockIdx.x*32, d0 = blockIdx.y*32;
  const int tx = threadIdx.x, ty = threadIdx.y;
  const int b = bk >> 2, kvh = bk & 3;
  #pragma unroll
  for (int i = 0; i < 32; i += 8)
    t[ty+i][tx] = QKV[(long)(b*S_ + s0+ty+i)*NQKV_ + 2560 + kvh*128 + d0 + tx];
  __syncthreads();
  #pragma unroll
  for (int i = 0; i < 32; i += 8)
    Vt[((long)bk*D_ + d0+ty+i)*S_ + s0 + tx] = t[tx][ty+i];
}

// ---------- bias concat ----------
__global__ void concat_bias(const float* bq, const float* bk, const float* bv, float* bqkv) {
  int i = blockIdx.x*256 + threadIdx.x;
  if (i < NQKV_)
    bqkv[i] = (i < 2048) ? bq[i] : ((i < 2560) ? bk[i-2048] : bv[i-2560]);
}

// ---------- rope tables (exp2 instead of powf) ----------
__global__ void rope_tab(float* __restrict__ cosb, float* __restrict__ sinb) {
  int i = blockIdx.x*256 + threadIdx.x;   // 2048*64
  int t = i >> 6, d = i & 63;
  // 10000^(-d/64) = exp2(-d * log2(10000)/64)
  float inv = exp2f(-(float)d * 0.20762050593045951f);
  float fr = (float)t * inv;
  float sv, cv;
  sincosf(fr, &sv, &cv);
  cosb[i] = cv; sinb[i] = sv;
}

// ---------- rope apply + scatter; QKV bf16; Q pre-scaled for exp2-domain softmax ----------
__global__ __launch_bounds__(256) void rope_qkv(
    const u16* __restrict__ QKV, const float* __restrict__ cosb, const float* __restrict__ sinb,
    u16* __restrict__ Qb, u16* __restrict__ Kb,
    float* __restrict__ kout, float* __restrict__ vout)
{
  const float QS = 0.08838834764831845f * 1.4426950408889634f;
  const int m = blockIdx.x;                 // b*S + s
  const int b = m >> 11, s = m & 2047;
  const int tid = threadIdx.x;
  const u16* row = QKV + (long)m * NQKV_;
  const int d = tid & 63;
  const float c  = cosb[s*64 + d];
  const float sn = sinb[s*64 + d];
  #pragma unroll
  for (int i = 0; i < 4; i++) {             // 16 q heads
    int hh = (tid + i*256) >> 6;
    float x1 = bf2f(row[hh*128 + d]), x2 = bf2f(row[hh*128 + d + 64]);
    float o1 = x1*c - x2*sn, o2 = x2*c + x1*sn;
    long base = ((long)(b*NQ_ + hh)*S_ + s)*D_;
    Qb[base + d] = f2bf(o1*QS);
    Qb[base + d + 64] = f2bf(o2*QS);
  }
  {                                          // 4 k heads
    int kh = tid >> 6;
    float x1 = bf2f(row[2048 + kh*128 + d]), x2 = bf2f(row[2048 + kh*128 + d + 64]);
    float o1 = x1*c - x2*sn, o2 = x2*c + x1*sn;
    long kb = ((long)(b*NKV_ + kh)*S_ + s)*D_;
    Kb[kb + d] = f2bf(o1);
    Kb[kb + d + 64] = f2bf(o2);
    long ko = ((long)m*NKV_ + kh)*D_;
    kout[ko + d] = o1;
    kout[ko + d + 64] = o2;
  }
  #pragma unroll
  for (int i = 0; i < 2; i++) {              // v passthrough
    int e = tid + i*256;
    vout[(long)m*512 + e] = bf2f(row[2560 + e]);
  }
}

// ---------- GEMM, 8-phase schedule (R12-proven) ----------
// C[M][N] = A[M][K](bf16) * B^T (B stored [N][K] bf16) + bias.
// BK=64, 512 threads = 8 waves (WM x WN). 4 phases/K-tile, Gray quadrant order.
// Stage map: P0:(t+1).A1, P1:(t+1).B0, P2:(t+2).A0, P3:(t+2).B1; stage issued
// BEFORE barrier#1. Boundary vmcnt(ALD+BLD); never 0 until the last tile.
template<int BM, int BN, int WN, typename OutT>
__global__ __launch_bounds__(512, 2) void gemm8p(
    const u16* __restrict__ A, const u16* __restrict__ Bm,
    const float* __restrict__ bias, OutT* __restrict__ C,
    int M, int N, int K)
{
  constexpr int WM  = 8 / WN;
  constexpr int RW  = (BM/2) / WM;           // per-wave row width within a half
  constexpr int JA  = RW / 16;               // A frags per half
  constexpr int CW  = (BN/2) / WN;           // per-wave col width within a half
  constexpr int JB  = CW / 16;               // B frags per half
  constexpr int ALD = BM/128;                // A loads/thread per half-tile
  constexpr int BLD = BN/128;                // B loads/thread per half-tile
  constexpr int VMC = ALD + BLD;             // newest half-tiles kept in flight
  __shared__ u16 As[2][BM*64];
  __shared__ u16 Bs[2][BN*64];

  const int tid = threadIdx.x;
  const int lane = tid & 63, w = tid >> 6;
  const int r16 = lane & 15, g = lane >> 4;
  const int wrn = w / WN, wcn = w % WN;

  const int gx = gridDim.x;
  const int nwg = gx * gridDim.y;
  const int id = blockIdx.y * gx + blockIdx.x;
  const int cpx = nwg >> 3;
  const int sid = (id & 7) * cpx + (id >> 3);
  const long m0 = (long)(sid / gx) * BM;
  const long n0 = (long)(sid % gx) * BN;

  const u16* Ag = A + m0 * K;
  const u16* Bg = Bm + n0 * K;

  auto stageA = [&](int buf, int h, int k0) {
    #pragma unroll
    for (int i = 0; i < ALD; i++) {
      const int slot = i*512 + tid;
      const int row = h*(BM/2) + (slot >> 3), cg = slot & 7;
      const u16* src = Ag + (long)row*K + k0 + ((cg ^ (row & 7)) * 8);
      gload_lds16(src, &As[buf][h*(BM*32) + slot*8]);
    }
  };
  auto stageB = [&](int buf, int h, int k0) {
    #pragma unroll
    for (int i = 0; i < BLD; i++) {
      const int slot = i*512 + tid;
      const int row = h*(BN/2) + (slot >> 3), cg = slot & 7;
      const u16* src = Bg + (long)row*K + k0 + ((cg ^ (row & 7)) * 8);
      gload_lds16(src, &Bs[buf][h*(BN*32) + slot*8]);
    }
  };

  f32x4 acc[2*JA][2*JB] = {};
  s16x8 Ar[JA][2], Br[JB][2];
  const int nt = K >> 6;

#define PHASE(BUF, MH, NH, RDA, RDB, STMT)                                        \
  do {                                                                            \
    if (RDA) {                                                                    \
      _Pragma("unroll") for (int j = 0; j < JA; j++)                              \
        _Pragma("unroll") for (int kk = 0; kk < 2; kk++) {                        \
          const int R = (MH)*(BM/2) + wrn*RW + j*16 + r16;                        \
          Ar[j][kk] = *(const s16x8*)&As[BUF][R*64 + (((kk*4 + g) ^ (R & 7))*8)]; \
        }                                                                         \
    }                                                                             \
    if (RDB) {                                                                    \
      _Pragma("unroll") for (int jj = 0; jj < JB; jj++)                           \
        _Pragma("unroll") for (int kk = 0; kk < 2; kk++) {                        \
          const int Cc = (NH)*(BN/2) + wcn*CW + jj*16 + r16;                      \
          Br[jj][kk] = *(const s16x8*)&Bs[BUF][Cc*64 + (((kk*4 + g) ^ (Cc & 7))*8)]; \
        }                                                                         \
    }                                                                             \
    STMT;                                                                         \
    __builtin_amdgcn_s_barrier();                                                 \
    asm volatile("s_waitcnt lgkmcnt(0)" ::: "memory");                            \
    __builtin_amdgcn_sched_barrier(0);                                            \
    __builtin_amdgcn_s_setprio(1);                                                \
    _Pragma("unroll") for (int j = 0; j < JA; j++)                                \
      _Pragma("unroll") for (int jj = 0; jj < JB; jj++)                           \
        _Pragma("unroll") for (int kk = 0; kk < 2; kk++)                          \
          acc[(MH)*JA + j][(NH)*JB + jj] =                                        \
            MFMA16(Ar[j][kk], Br[jj][kk], acc[(MH)*JA + j][(NH)*JB + jj]);        \
    __builtin_amdgcn_s_setprio(0);                                                \
    __builtin_amdgcn_s_barrier();                                                 \
  } while (0)

  // prologue: tile0 all 4 halves; tile1's A0 and B1
  stageA(0, 0, 0); stageA(0, 1, 0); stageB(0, 0, 0); stageB(0, 1, 0);
  if (nt > 1) { stageA(1, 0, 64); stageB(1, 1, 64); }

  for (int t = 0; t < nt; t++) {
    const int X = t & 1, Y = X ^ 1;
    if (t == nt - 1) {
      asm volatile("s_waitcnt vmcnt(0)" ::: "memory");
    } else if constexpr (VMC == 4) {
      asm volatile("s_waitcnt vmcnt(4)" ::: "memory");
    } else {
      asm volatile("s_waitcnt vmcnt(3)" ::: "memory");
    }
    __builtin_amdgcn_s_barrier();
    PHASE(X, 0, 0, true,  true,  { if (t+1 < nt) stageA(Y, 1, (t+1)*64); });
    PHASE(X, 0, 1, false, true,  { if (t+1 < nt) stageB(Y, 0, (t+1)*64); });
    PHASE(X, 1, 1, true,  false, { if (t+2 < nt) stageA(X, 0, (t+2)*64); });
    PHASE(X, 1, 0, false, true,  { if (t+2 < nt) stageB(X, 1, (t+2)*64); });
  }
#undef PHASE

  #pragma unroll
  for (int mh = 0; mh < 2; mh++)
    #pragma unroll
    for (int j = 0; j < JA; j++)
      #pragma unroll
      for (int nh = 0; nh < 2; nh++)
        #pragma unroll
        for (int jj = 0; jj < JB; jj++) {
          const int col = nh*(BN/2) + wcn*CW + jj*16 + r16;
          const float bv = bias[n0 + col];
          #pragma unroll
          for (int r = 0; r < 4; r++) {
            const long row = m0 + mh*(BM/2) + wrn*RW + j*16 + g*4 + r;
            const float vv = acc[mh*JA + j][nh*JB + jj][r] + bv;
            if constexpr (sizeof(OutT) == 2)
              C[row * N + n0 + col] = (OutT)f2bf(vv);
            else
              C[row * N + n0 + col] = (OutT)vv;
          }
        }
}

// ---------- flash attention v7 (R9/R12/R15-proven: 73.5us) ----------
__global__ __launch_bounds__(256, 2) void attn_kernel(
    const u16* __restrict__ Qb, const u16* __restrict__ Kb,
    const u16* __restrict__ Vt, u16* __restrict__ Ob)
{
  __shared__ u16 Ks[2][64*128];      // [kv][d], granule^(kv&15)
  __shared__ u16 Vs[2][64*128];      // [d&63][(d>>6)*64+kv], granule^(d2&15)
  const int tid = threadIdx.x;
  const int lane = tid & 63, w = tid >> 6;   // 4 waves
  const int l31 = lane & 31, hi = lane >> 5;
  const int id = blockIdx.x;                 // 512 blocks
  const int bh = id & 31;
  const int b = bh >> 4, h = bh & 15;
  const int p = id >> 5;                     // 0..15
  const int qt = (p < 8) ? (15 - p) : (p - 8);  // long blocks first
  const int kvh = h >> 2;
  const int q0w = qt*128 + w*32;
  const int nt = 2*qt + 2;                   // even

  const u16* Qg = Qb + (((long)(b*NQ_ + h))*S_ + q0w)*D_;
  const u16* Kg = Kb + ((long)(b*NKV_ + kvh))*S_*D_;
  const u16* Vg = Vt + ((long)(b*NKV_ + kvh))*D_*S_;

  s16x8 qf[8];
  #pragma unroll
  for (int ks = 0; ks < 8; ks++)
    qf[ks] = *(const s16x8*)&Qg[l31*D_ + ks*16 + hi*8];

  f32x16 po[4] = {};                 // O[q(reg)][d = dt*32 + l31]
  float mrow = -1e30f, lrow = 0.f;

  auto stage = [&](int buf, int kv0s) {
    #pragma unroll
    for (int i = 0; i < 4; i++) {
      const int c = i*4 + w;                 // 16 chunks of 1KB
      const int G = c*64 + lane;
      const int krow = G >> 4, kcg = G & 15;
      const u16* gk = Kg + (long)(kv0s + krow)*D_ + ((kcg ^ (krow & 15)) * 8);
      gload_lds16(gk, &Ks[buf][c*512]);
      const int o = c*512 + lane*8;
      const int d2 = o >> 7, t16 = (o >> 3) & 15;
      const int gidx = t16 ^ (d2 & 15);
      const int dsr = ((gidx >> 3) << 6) + d2;
      const u16* gv = Vg + (long)dsr*S_ + kv0s + ((gidx & 7) * 8);
      gload_lds16(gv, &Vs[buf][c*512]);
    }
  };

  // compute one 64-kv step from buffer `buf` (call with literal buf!)
  auto compute = [&](int buf, int t) {
    const int kv0 = t*64;
    if (kv0 > q0w + 31) return;
    f32x16 sc[2] = {};
    __builtin_amdgcn_s_setprio(1);
    #pragma unroll
    for (int ks = 0; ks < 8; ks++) {
      #pragma unroll
      for (int ct = 0; ct < 2; ct++) {
        const int row = ct*32 + l31;
        s16x8 kf = *(const s16x8*)&Ks[buf][row*128 + ((ks*16 + hi*8) ^ ((row & 15)*8))];
        sc[ct] = MFMA32(kf, qf[ks], sc[ct]);
      }
    }
    __builtin_amdgcn_s_setprio(0);
    if (kv0 + 63 > q0w) {
      const int qrow = q0w + l31;
      #pragma unroll
      for (int ct = 0; ct < 2; ct++)
        #pragma unroll
        for (int r = 0; r < 16; r++) {
          int kv = kv0 + ct*32 + (r & 3) + 8*(r >> 2) + 4*hi;
          if (kv > qrow) sc[ct][r] = -3.0e38f;
        }
    }
    float pm = sc[0][0];
    #pragma unroll
    for (int ct = 0; ct < 2; ct++)
      #pragma unroll
      for (int r = 0; r < 16; r++) pm = fmaxf(pm, sc[ct][r]);
    pm = fmaxf(pm, __shfl_xor(pm, 32, 64));
    if (!__all(pm - mrow <= 8.0f)) {       // defer-max (T13)
      float mn = fmaxf(mrow, pm);
      float fr = exp2f(mrow - mn);
      mrow = mn;
      lrow *= fr;
      #pragma unroll
      for (int r = 0; r < 16; r++) {
        float frv = __shfl(fr, (r & 3) + 8*(r >> 2) + 4*hi, 64);
        #pragma unroll
        for (int dt = 0; dt < 4; dt++) po[dt][r] *= frv;
      }
    }
    float ps = 0.f;
    #pragma unroll
    for (int ct = 0; ct < 2; ct++)
      #pragma unroll
      for (int r = 0; r < 16; r++) {
        float pv = exp2f(sc[ct][r] - mrow);
        sc[ct][r] = pv;
        ps += pv;
      }
    ps += __shfl_xor(ps, 32, 64);
    lrow += ps;
    unsigned mw[2][8];
    #pragma unroll
    for (int ct = 0; ct < 2; ct++)
      #pragma unroll
      for (int wd = 0; wd < 8; wd++)
        mw[ct][wd] = cvtpk(sc[ct][2*wd], sc[ct][2*wd + 1]);
    s16x8 pa[4];
    #pragma unroll
    for (int ct = 0; ct < 2; ct++)
      #pragma unroll
      for (int pp = 0; pp < 2; pp++) {
        unsigned a0 = mw[ct][4*pp + 0], b0 = mw[ct][4*pp + 2];
        unsigned a1 = mw[ct][4*pp + 1], b1 = mw[ct][4*pp + 3];
        plswap(a0, b0);
        plswap(a1, b1);
        union { unsigned u[4]; s16x8 v; } pu;
        pu.u[0] = a0; pu.u[1] = a1; pu.u[2] = b0; pu.u[3] = b1;
        pa[ct*2 + pp] = pu.v;
      }
    __builtin_amdgcn_s_setprio(1);
    #pragma unroll
    for (int ks2 = 0; ks2 < 4; ks2++)
      #pragma unroll
      for (int dt = 0; dt < 4; dt++) {
        const int d = dt*32 + l31, d2 = d & 63;
        const int gidx = ((d >> 6) << 3) + ks2*2 + hi;
        s16x8 vf = *(const s16x8*)&Vs[buf][d2*128 + ((gidx ^ (d2 & 15)) * 8)];
        po[dt] = MFMA32(pa[ks2], vf, po[dt]);
      }
    __builtin_amdgcn_s_setprio(0);
  };

  stage(0, 0);
  for (int t = 0; t < nt; t += 2) {
    stage(1, (t + 1)*64);
    asm volatile("s_waitcnt vmcnt(8)" ::: "memory");
    __builtin_amdgcn_s_barrier();
    compute(0, t);
    __builtin_amdgcn_s_barrier();
    if (t + 2 < nt) {
      stage(0, (t + 2)*64);
      asm volatile("s_waitcnt vmcnt(8)" ::: "memory");
    } else {
      asm volatile("s_waitcnt vmcnt(0)" ::: "memory");
    }
    __builtin_amdgcn_s_barrier();
    compute(1, t + 1);
    __builtin_amdgcn_s_barrier();
  }

  float inv = 1.0f / lrow;
  #pragma unroll
  for (int r = 0; r < 16; r++) {
    const int qr = (r & 3) + 8*(r >> 2) + 4*hi;
    float invq = __shfl(inv, qr, 64);
    const long q = (long)q0w + qr;
    #pragma unroll
    for (int dt = 0; dt < 4; dt++)
      Ob[((long)b*S_ + q)*H_ + h*D_ + dt*32 + l31] = f2bf(po[dt][r]*invq);
  }
}

// ---------- launcher ----------
extern "C" void kernel_launch(void* const* d_in, const int* in_sizes, int n_in,
                              void* d_out, int out_size, void* d_ws, size_t ws_size,
                              hipStream_t stream) {
  const float* hs = (const float*)d_in[0];
  const float* Wq = (const float*)d_in[1];
  const float* bq = (const float*)d_in[2];
  const float* Wk = (const float*)d_in[3];
  const float* bk = (const float*)d_in[4];
  const float* Wv = (const float*)d_in[5];
  const float* bv = (const float*)d_in[6];
  const float* Wc = (const float*)d_in[7];
  const float* bc = (const float*)d_in[8];

  float* out  = (float*)d_out;                  // (B,S,H)
  float* kout = out + (long)M_*H_;              // (B,S,NKV,D)
  float* vout = kout + (long)M_*NKV_*D_;        // (B,S,NKV,D)

  char* ws = (char*)d_ws;
  u16*  Xbf   = (u16*)ws;                                   // [4096][2048]
  u16*  Wqkvt = Xbf + (long)M_*H_;                          // [3072][2048]
  u16*  Wct   = Wqkvt + (long)NQKV_*H_;                     // [2048][2048]
  float* bqkv = (float*)(Wct + (long)H_*H_);                // [3072]
  u16*  QKV   = (u16*)(bqkv + NQKV_);                       // [4096][3072] bf16
  float* cosb = (float*)(QKV + (long)M_*NQKV_);             // [2048][64]
  float* sinb = cosb + S_*64;
  u16*  Qbf   = (u16*)(sinb + S_*64);                       // [B][NQ][S][D] (pre-scaled)
  u16*  Kbf   = Qbf + (long)B_*NQ_*S_*D_;                   // [B][NKV][S][D]
  u16*  Vtb   = Kbf + (long)B_*NKV_*S_*D_;                  // [B][NKV][D][S]
  u16*  Obf   = Vtb + (long)B_*NKV_*D_*S_;                  // [4096][2048]

  cvt_x<<<2048, 256, 0, stream>>>(hs, Xbf, (long)M_*H_/4);
  wtrans<<<dim3(64,64), dim3(32,8), 0, stream>>>(Wq, Wqkvt, 2048, 2048);
  wtrans<<<dim3(16,64), dim3(32,8), 0, stream>>>(Wk, Wqkvt + 2048L*2048, 512, 2048);
  wtrans<<<dim3(16,64), dim3(32,8), 0, stream>>>(Wv, Wqkvt + 2560L*2048, 512, 2048);
  wtrans<<<dim3(64,64), dim3(32,8), 0, stream>>>(Wc, Wct, 2048, 2048);
  concat_bias<<<12, 256, 0, stream>>>(bq, bk, bv, bqkv);
  rope_tab<<<512, 256, 0, stream>>>(cosb, sinb);

  // QKV: BM=128, BN=384 -> grid 8x32 = 256 blocks (full machine)
  gemm8p<128, 384, 4, u16><<<dim3(NQKV_/384, M_/128), 512, 0, stream>>>(
      Xbf, Wqkvt, bqkv, QKV, M_, NQKV_, H_);
  rope_qkv<<<M_, 256, 0, stream>>>(QKV, cosb, sinb, Qbf, Kbf, kout, vout);
  vtrans<<<dim3(S_/32, D_/32, B_*NKV_), dim3(32,8), 0, stream>>>(QKV, Vtb);
  attn_kernel<<<dim3(512), 256, 0, stream>>>(Qbf, Kbf, Vtb, Obf);
  // out-proj: BM=256, BN=128 -> grid 16x16 = 256 blocks
  gemm8p<256, 128, 2, float><<<dim3(H_/128, M_/256), 512, 0, stream>>>(
      Obf, Wct, bc, out, M_, H_, H_);
}